// Round 8
// baseline (193.101 us; speedup 1.0000x reference)
//
#include <hip/hip_runtime.h>

typedef __attribute__((ext_vector_type(8))) short bf16x8;
typedef __attribute__((ext_vector_type(4))) float f32x4;

#define MFMA16(a,b,c) __builtin_amdgcn_mfma_f32_16x16x32_bf16((a),(b),(c),0,0,0)

__device__ __forceinline__ float b2f(unsigned short u){
  union { unsigned u; float f; } x; x.u = ((unsigned)u) << 16; return x.f;
}
__device__ __forceinline__ unsigned short f2b(float f){
  union { float f; unsigned u; } x; x.f = f;
  unsigned r = x.u + 0x7FFFu + ((x.u >> 16) & 1u);
  return (unsigned short)(r >> 16);
}
__device__ __forceinline__ unsigned pk_rne(float a, float b){
  unsigned ua = __float_as_uint(a), ub = __float_as_uint(b);
  ua += 0x7FFFu + ((ua >> 16) & 1u);
  ub += 0x7FFFu + ((ub >> 16) & 1u);
  return __builtin_amdgcn_perm(ub, ua, 0x07060302u);
}
__device__ __forceinline__ unsigned pk_trunc(float a, float b){
  return __builtin_amdgcn_perm(__float_as_uint(b), __float_as_uint(a), 0x07060302u);
}
__device__ __forceinline__ bf16x8 mk8(unsigned a, unsigned b, unsigned c, unsigned d){
  union { uint4 u; bf16x8 h; } x; x.u = make_uint4(a,b,c,d); return x.h;
}
// cluster-index bit rotation so register Sᵀ fragments align with PV's B-operand k-slots
__device__ __forceinline__ int permp(int cl){
  return (cl & 0xE0) | (((cl >> 2) & 3) << 3) | (((cl >> 4) & 1) << 2) | (cl & 3);
}

typedef __attribute__((address_space(3))) unsigned int lds_u32;
typedef const __attribute__((address_space(1))) unsigned int glb_u32;
__device__ __forceinline__ void gl_lds16(const void* g, void* l){
  __builtin_amdgcn_global_load_lds((glb_u32*)g, (lds_u32*)l, 16, 0, 0);
}

// ---------------- merged prep + cluster means ----------------
__global__ __launch_bounds__(192) void prep_means_kernel(
    const float* __restrict__ pos, unsigned* __restrict__ pmax,
    const float* __restrict__ qkv_w, unsigned short* __restrict__ qkvwb,
    const float* __restrict__ proj_w, unsigned short* __restrict__ projwb,
    const float* __restrict__ feat,
    const int* __restrict__ member_idx, const int* __restrict__ batch_idx,
    unsigned short* __restrict__ fm, float* __restrict__ pm,
    unsigned short* __restrict__ featb)
{
  int bid = blockIdx.x, t = threadIdx.x;
  if (bid < 1024){
    int g = t / 96, tl = t - g*96;
    int z = bid;
    __shared__ int bases[32];
    __shared__ float4 part[96];
    if (t < 32) bases[t] = batch_idx[z*32 + t]*8192 + member_idx[z*32 + t];
    __syncthreads();
    // pos mean: one wave-load + tree reduce on lanes 0..31
    if (t < 32){
      float2 pp = ((const float2*)pos)[bases[t]];
      #pragma unroll
      for (int off = 16; off >= 1; off >>= 1){
        pp.x += __shfl_xor(pp.x, off, 32);
        pp.y += __shfl_xor(pp.y, off, 32);
      }
      if (t == 0){ pm[z*2] = pp.x*(1.f/32.f); pm[z*2+1] = pp.y*(1.f/32.f); }
    }
    // feat: 16 gather loads in flight, then stores + accumulate
    float4 v[16]; int rows[16];
    const float4* f4 = (const float4*)feat;
    #pragma unroll
    for (int m = 0; m < 16; m++){
      rows[m] = bases[g*16 + m];
      v[m] = f4[(long)rows[m]*96 + tl];
    }
    float4 a = {0.f,0.f,0.f,0.f};
    #pragma unroll
    for (int m = 0; m < 16; m++){
      *(uint2*)(featb + (long)rows[m]*384 + tl*4) =
          make_uint2(pk_rne(v[m].x, v[m].y), pk_rne(v[m].z, v[m].w));
      a.x += v[m].x; a.y += v[m].y; a.z += v[m].z; a.w += v[m].w;
    }
    if (g == 1) part[tl] = a;
    __syncthreads();
    if (g == 0){
      float4 b = part[tl];
      a.x += b.x; a.y += b.y; a.z += b.z; a.w += b.w;
      unsigned d0 = pk_rne(a.x*(1.f/32.f), a.y*(1.f/32.f));
      unsigned d1 = pk_rne(a.z*(1.f/32.f), a.w*(1.f/32.f));
      *(uint2*)(fm + (long)z*384 + tl*4) = make_uint2(d0, d1);
    }
  } else if (bid < 1408){
    int u = (bid - 1024)*192 + t;     // [0, 73728)
    const float* in; unsigned short* o; long i;
    if (u < 55296){ in = qkv_w;  o = qkvwb;  i = u; }
    else          { in = proj_w; o = projwb; i = u - 55296; }
    const float4* p = (const float4*)(in + i*8);
    float4 a = p[0], b = p[1];
    *(uint4*)(o + i*8) = make_uint4(pk_rne(a.x,a.y), pk_rne(a.z,a.w),
                                    pk_rne(b.x,b.y), pk_rne(b.z,b.w));
  } else {
    int i = (bid - 1408)*192 + t;
    if (i < 16384){
      float4 v = ((const float4*)pos)[i];
      float m0 = fmaxf(v.x, v.z), m1 = fmaxf(v.y, v.w);
      #pragma unroll
      for (int off = 32; off >= 1; off >>= 1){
        m0 = fmaxf(m0, __shfl_xor(m0, off, 64));
        m1 = fmaxf(m1, __shfl_xor(m1, off, 64));
      }
      if ((t & 63) == 0){
        atomicMax(&pmax[0], __float_as_uint(m0));
        atomicMax(&pmax[1], __float_as_uint(m1));
      }
    }
  }
}

// ---------------- merged kv-GEMM + wt + q-GEMM, 512 blocks ----------------
__global__ __launch_bounds__(512) void kvq_kernel(
    const unsigned short* __restrict__ fm,     // (1024,384) bf16 cluster means
    const unsigned short* __restrict__ featb,  // (32768,384) bf16
    const unsigned short* __restrict__ qkvwb,  // (1152,384) bf16; rows 0..383 = Wq
    const float* __restrict__ qkv_b,           // (1152)
    const float* __restrict__ pm, const float* __restrict__ pmaxf,
    const float* __restrict__ pos_w, const float* __restrict__ pos_b,
    unsigned short* __restrict__ kh, unsigned short* __restrict__ vt,
    unsigned short* __restrict__ wt,
    unsigned short* __restrict__ q_s, float q_scale)
{
  __shared__ unsigned short As[64*64];    // 8 KB
  __shared__ unsigned short Ws[384*64];   // 48 KB
  __shared__ unsigned short wtS[256];
  const int K = 384;
  int tid = threadIdx.x;
  int lane = tid & 63, wave = tid >> 6;
  int l15 = lane & 15, quad = lane >> 4;
  int sw = l15 & 7;
  int srow = tid >> 3, sc8 = tid & 7;     // 512 thr: srow 0..63

  int qtile;
  if (blockIdx.x < 96){
    // ================= kv GEMM =================
    int mt = blockIdx.x / 6, nt = blockIdx.x - mt*6;
    int m0 = mt << 6, n0 = nt << 7;
    int b = m0 >> 8, cl0 = m0 & 255;
    const unsigned short* W = qkvwb + 384*384;
    // wt prologue: this block's 4 heads x 64 clusters (bit-identical to old bias_kernel)
    if (nt >= 3 && tid < 256){
      int lh = tid >> 6, lc = tid & 63;
      int h = ((n0 - 384) >> 5) + lh;
      int cl = cl0 + lc;
      float p0 = pm[(b*256 + cl)*2]   / pmaxf[0];
      float p1 = pm[(b*256 + cl)*2+1] / pmaxf[1];
      float bias = p0*pos_w[h*2] + p1*pos_w[h*2+1] + pos_b[h];
      unsigned short wv = f2b(exp2f(bias * 1.44269504088896340f));
      wtS[lh*64 + lc] = wv;
      wt[(((long)(b*12 + h)) << 8) + permp(cl)] = wv;
    }
    int wr = (wave >> 2) << 5, wc = (wave & 3) << 5;
    f32x4 acc[2][2];
    #pragma unroll
    for (int i = 0; i < 2; i++)
      #pragma unroll
      for (int j = 0; j < 2; j++) acc[i][j] = (f32x4){0.f,0.f,0.f,0.f};

    for (int k0 = 0; k0 < K; k0 += 64){
      __syncthreads();
      int gc8 = sc8 ^ (srow & 7);
      gl_lds16(fm + (long)(m0+srow)*K + k0 + gc8*8, As + wave*512);
      #pragma unroll
      for (int it = 0; it < 2; it++){
        int r = it*64 + srow;
        int g2 = sc8 ^ (r & 7);
        gl_lds16(W + (long)(n0+r)*K + k0 + g2*8, Ws + it*4096 + wave*512);
      }
      __syncthreads();
      #pragma unroll
      for (int kk = 0; kk < 2; kk++){
        bf16x8 af[2], bfr[2];
        #pragma unroll
        for (int i = 0; i < 2; i++)
          af[i] = *(const bf16x8*)(As + (wr + i*16 + l15)*64 + (((kk<<2)+quad) ^ sw)*8);
        #pragma unroll
        for (int j = 0; j < 2; j++)
          bfr[j] = *(const bf16x8*)(Ws + (wc + j*16 + l15)*64 + (((kk<<2)+quad) ^ sw)*8);
        #pragma unroll
        for (int i = 0; i < 2; i++)
          #pragma unroll
          for (int j = 0; j < 2; j++)
            acc[i][j] = MFMA16(af[i], bfr[j], acc[i][j]);
      }
    }

    #pragma unroll
    for (int j = 0; j < 2; j++){
      int col = n0 + wc + j*16 + l15;
      float bv = qkv_b[384 + col];
      #pragma unroll
      for (int i = 0; i < 2; i++){
        #pragma unroll
        for (int r = 0; r < 4; r++){
          float v = acc[i][j][r] + bv;
          int lr = wr + i*16 + quad*4 + r;     // local row 0..63
          int cl = cl0 + lr;
          if (col < 384){
            int h = col >> 5, ch = col & 31;
            kh[((((long)b*12 + h)*256 + cl)*32) + ch] = f2b(v);
          } else {
            int cn = col - 384;
            int h = cn >> 5, ch = cn & 31;
            int pp = permp(cl);
            int c8 = (pp >> 3) ^ (ch & 7);
            float w = b2f(wtS[(wave & 3)*64 + lr]);
            vt[(((long)b*12 + h)*32 + ch)*256 + c8*8 + (pp & 7)] = f2b(v * w);
          }
        }
      }
    }
    qtile = 416 + blockIdx.x;
  } else {
    qtile = blockIdx.x - 96;
  }

  // ================= q GEMM (single-buffer, 2 blocks/CU structure) =================
  {
    int m0 = qtile << 6;
    f32x4 acc[4][3];
    #pragma unroll
    for (int i = 0; i < 4; i++)
      #pragma unroll
      for (int j = 0; j < 3; j++) acc[i][j] = (f32x4){0.f,0.f,0.f,0.f};

    for (int k0 = 0; k0 < K; k0 += 64){
      __syncthreads();
      int gc8 = sc8 ^ (srow & 7);
      gl_lds16(featb + (long)(m0+srow)*K + k0 + gc8*8, As + wave*512);
      #pragma unroll
      for (int it = 0; it < 6; it++){
        int r = it*64 + srow;
        int g2 = sc8 ^ (r & 7);
        gl_lds16(qkvwb + (long)r*K + k0 + g2*8, Ws + it*4096 + wave*512);
      }
      __syncthreads();
      #pragma unroll
      for (int kk = 0; kk < 2; kk++){
        bf16x8 af[4];
        #pragma unroll
        for (int i = 0; i < 4; i++)
          af[i] = *(const bf16x8*)(As + (i*16 + l15)*64 + (((kk<<2)+quad) ^ sw)*8);
        #pragma unroll
        for (int j = 0; j < 3; j++){
          bf16x8 bfr = *(const bf16x8*)(Ws + (wave*48 + j*16 + l15)*64 + (((kk<<2)+quad) ^ sw)*8);
          #pragma unroll
          for (int i = 0; i < 4; i++)
            acc[i][j] = MFMA16(af[i], bfr, acc[i][j]);
        }
      }
    }

    #pragma unroll
    for (int j = 0; j < 3; j++){
      int col = wave*48 + j*16 + l15;
      float bv = qkv_b[col];
      #pragma unroll
      for (int i = 0; i < 4; i++){
        int row0 = m0 + i*16 + quad*4;
        #pragma unroll
        for (int r = 0; r < 4; r++){
          float v = (acc[i][j][r] + bv) * q_scale;
          int row = row0 + r;
          int bb = row >> 13, tok = row & 8191;
          q_s[((((long)(bb*12 + (col >> 5))) << 13) + tok)*32 + (col & 31)] = f2b(v);
        }
      }
    }
  }
}

// ---------------- FUSED attention + proj (128 tok/block, 2 tiles/wave, K-swizzle) ----------------
// block = (b, 128 tokens), 512 thr / 8 waves, 256 blocks = 1/CU (81 KB LDS).
// 6 iterations x head-pair: waves 0-3 = h0 (tiles w4, w4+4), waves 4-7 = h1.
// Round-7 fixes (counter-driven):
//  * keyS XOR-swizzle col8 ^= (row>>1)&3 (pre-swizzled GLOBAL src, m173 pattern)
//    -> kills the 3.3M 8-way K-read bank conflicts (64 B row stride).
//  * 2 tiles/wave: each K/V/w fragment read feeds 10 MFMAs (was 5) -> per-CU
//    LDS-pipe cycles halve; K/V staging traffic per token halves.
__global__ __launch_bounds__(512, 2) void attnproj_kernel(
    const unsigned short* __restrict__ qhm,    // (B*H,8192,32) bf16, scale*log2e folded
    const unsigned short* __restrict__ kh,     // (B,H,256,32) bf16
    const unsigned short* __restrict__ vt,     // (B,H,32,256) bf16, permp+swizzled, w-folded
    const unsigned short* __restrict__ wt,     // (B*H,256) bf16, permp'd
    const unsigned short* __restrict__ projwb, // (384,384) bf16
    const float* __restrict__ proj_b,
    float* __restrict__ out)                   // (B*8192,384) f32
{
  __shared__ unsigned short keyS[16384];       // 32 KB: [head][256][32], col8^=(row>>1)&3
  __shared__ unsigned short vTS[16384];        // 32 KB: [head][32][256] swizzled
  __shared__ unsigned short oS[128*64];        // 16 KB: [tok][ch oct^sw]
  __shared__ unsigned short wS[512];           // 1 KB: [head][256]

  int bid = blockIdx.x;
  int b = bid >> 6;
  int t0 = (bid & 63) << 7;                    // 128 tokens
  int tid = threadIdx.x, lane = tid & 63, wave = tid >> 6;
  int l15 = lane & 15, quad = lane >> 4;
  int sw = l15 & 7;
  int hsel = wave >> 2, w4 = wave & 3;

  f32x4 acc[8][3];
  #pragma unroll
  for (int i = 0; i < 8; i++)
    #pragma unroll
    for (int j = 0; j < 3; j++) acc[i][j] = (f32x4){0.f,0.f,0.f,0.f};

  for (int it = 0; it < 6; it++){
    int h0 = 2*it;
    const unsigned short* ks = kh + ((long)b*12 + h0)*8192;   // 2 heads contiguous
    const unsigned short* vs = vt + ((long)b*12 + h0)*8192;
    #pragma unroll
    for (int p = 0; p < 4; p++){
      // K: pre-swizzled global source (LDS dest is linear: base + lane*16)
      int u = p*512 + wave*64 + lane;          // 16B unit index, 0..2047
      int krow = u >> 2;                       // 0..511 across 2 heads
      int kc = (u & 3) ^ ((krow >> 1) & 3);
      gl_lds16(ks + krow*32 + kc*8, keyS + p*4096 + wave*512);
      gl_lds16(vs + p*4096 + tid*8, vTS + p*4096 + wave*512);
    }
    if (wave == 0)
      gl_lds16(wt + ((long)b*12 + h0)*256 + lane*8, wS);

    // q prefetch for both tiles (global; overlaps staging)
    long bh = (long)b*12 + h0 + hsel;
    long qb = (bh*8192 + t0 + w4*16 + l15)*32 + quad*8;
    bf16x8 aq0 = *(const bf16x8*)(qhm + qb);
    bf16x8 aq1 = *(const bf16x8*)(qhm + qb + 2048);   // +64 tokens
    __syncthreads();                          // stage drained (vmcnt0 before barrier)

    const unsigned short* kb = keyS + hsel*8192;
    const unsigned short* vb = vTS  + hsel*8192;
    const unsigned short* wb = wS   + hsel*256;

    f32x4 o00 = {0.f,0.f,0.f,0.f}, o01 = {0.f,0.f,0.f,0.f}, os0 = {0.f,0.f,0.f,0.f};
    f32x4 o10 = {0.f,0.f,0.f,0.f}, o11 = {0.f,0.f,0.f,0.f}, os1 = {0.f,0.f,0.f,0.f};
    #pragma unroll
    for (int ks8 = 0; ks8 < 8; ks8++){
      int r0 = 2*ks8*16 + l15;                // local K row, tile row 2*ks8
      int r1 = r0 + 16;
      bf16x8 bk0 = *(const bf16x8*)(kb + r0*32 + ((quad ^ ((r0 >> 1) & 3)))*8);
      bf16x8 bk1 = *(const bf16x8*)(kb + r1*32 + ((quad ^ ((r1 >> 1) & 3)))*8);
      const f32x4 z4 = {0.f,0.f,0.f,0.f};
      f32x4 s00 = MFMA16(bk0, aq0, z4);
      f32x4 s01 = MFMA16(bk1, aq0, z4);
      f32x4 s10 = MFMA16(bk0, aq1, z4);
      f32x4 s11 = MFMA16(bk1, aq1, z4);
      #pragma unroll
      for (int c = 0; c < 4; c++){
        s00[c] = exp2f(s00[c]); s01[c] = exp2f(s01[c]);
        s10[c] = exp2f(s10[c]); s11[c] = exp2f(s11[c]);
      }
      bf16x8 pf0 = mk8(pk_trunc(s00[0],s00[1]), pk_trunc(s00[2],s00[3]),
                       pk_trunc(s01[0],s01[1]), pk_trunc(s01[2],s01[3]));
      bf16x8 pf1 = mk8(pk_trunc(s10[0],s10[1]), pk_trunc(s10[2],s10[3]),
                       pk_trunc(s11[0],s11[1]), pk_trunc(s11[2],s11[3]));
      int c8 = (4*ks8 + quad) ^ sw;
      bf16x8 a0 = *(const bf16x8*)(vb + l15*256      + c8*8);
      bf16x8 a1 = *(const bf16x8*)(vb + (16+l15)*256 + c8*8);
      bf16x8 wf = *(const bf16x8*)(wb + ks8*32 + quad*8);
      o00 = MFMA16(a0, pf0, o00);
      o01 = MFMA16(a1, pf0, o01);
      os0 = MFMA16(wf, pf0, os0);
      o10 = MFMA16(a0, pf1, o10);
      o11 = MFMA16(a1, pf1, o11);
      os1 = MFMA16(wf, pf1, os1);
    }

    // normalize + store O tiles [128 tok][64 ch] bf16 with oct^sw swizzle
    // (bf16-rounded at the same point as the old global ao write -> bit-identical)
    float inv0 = 1.f / os0[0];
    float inv1 = 1.f / os1[0];
    int oct0 = hsel*4 + (quad >> 1);
    int wi = (quad & 1)*4;
    int tokLoc0 = w4*16 + l15;
    *(uint2*)(oS + tokLoc0*64 + ((oct0 ^ sw)*8 + wi)) =
        make_uint2(pk_rne(o00[0]*inv0, o00[1]*inv0), pk_rne(o00[2]*inv0, o00[3]*inv0));
    *(uint2*)(oS + tokLoc0*64 + (((oct0+2) ^ sw)*8 + wi)) =
        make_uint2(pk_rne(o01[0]*inv0, o01[1]*inv0), pk_rne(o01[2]*inv0, o01[3]*inv0));
    int tokLoc1 = tokLoc0 + 64;
    *(uint2*)(oS + tokLoc1*64 + ((oct0 ^ sw)*8 + wi)) =
        make_uint2(pk_rne(o10[0]*inv1, o10[1]*inv1), pk_rne(o10[2]*inv1, o10[3]*inv1));
    *(uint2*)(oS + tokLoc1*64 + (((oct0+2) ^ sw)*8 + wi)) =
        make_uint2(pk_rne(o11[0]*inv1, o11[1]*inv1), pk_rne(o11[2]*inv1, o11[3]*inv1));
    __syncthreads();                          // O visible; keyS/vTS reads complete

    // proj accumulate: BK=64 (this head-pair's channels); B direct from L2
    #pragma unroll
    for (int kk = 0; kk < 2; kk++){
      bf16x8 af[8];
      #pragma unroll
      for (int i = 0; i < 8; i++)
        af[i] = *(const bf16x8*)(oS + (i*16 + l15)*64 + (((kk<<2)+quad) ^ sw)*8);
      #pragma unroll
      for (int j = 0; j < 3; j++){
        bf16x8 bfr = *(const bf16x8*)(projwb + (long)(wave*48 + j*16 + l15)*384
                                      + it*64 + (kk*4 + quad)*8);
        #pragma unroll
        for (int i = 0; i < 8; i++)
          acc[i][j] = MFMA16(af[i], bfr, acc[i][j]);
      }
    }
    // no barrier: next stage writes keyS/vTS only; next oS write is after the
    // next barrier, by which time all proj oS reads are done (program order).
  }

  // epilogue: f32 token-major
  #pragma unroll
  for (int j = 0; j < 3; j++){
    int col = wave*48 + j*16 + l15;
    float bv = proj_b[col];
    #pragma unroll
    for (int i = 0; i < 8; i++){
      long row0 = (long)b*8192 + t0 + i*16 + quad*4;
      #pragma unroll
      for (int r = 0; r < 4; r++)
        out[(row0 + r)*384 + col] = acc[i][j][r] + bv;
    }
  }
}

extern "C" void kernel_launch(void* const* d_in, const int* in_sizes, int n_in,
                              void* d_out, int out_size, void* d_ws, size_t ws_size,
                              hipStream_t stream)
{
  const float* pos      = (const float*)d_in[0];
  const float* feat     = (const float*)d_in[1];
  const int* member_idx = (const int*)d_in[2];
  const int* batch_idx  = (const int*)d_in[3];
  const float* qkv_w    = (const float*)d_in[4];
  const float* qkv_b    = (const float*)d_in[5];
  const float* pos_w    = (const float*)d_in[6];
  const float* pos_b    = (const float*)d_in[7];
  const float* proj_w   = (const float*)d_in[8];
  const float* proj_b   = (const float*)d_in[9];
  float* out = (float*)d_out;

  char* ws = (char*)d_ws;
  float* pmax           = (float*)ws;                       // 8 B
  float* pm             = (float*)(ws + 256);               // 8 KB
  unsigned short* fm    = (unsigned short*)(ws + 8704);     // 1024x384 bf16
  unsigned short* kh    = (unsigned short*)(ws + 795136);   // 4x12x256x32 bf16
  unsigned short* vt    = (unsigned short*)(ws + 1581568);  // 4x12x32x256 bf16
  unsigned short* wt    = (unsigned short*)(ws + 2368000);  // 4x12x256 bf16
  unsigned short* q_s   = (unsigned short*)(ws + 2417152);  // 48x8192x32 bf16 (head-major)
  unsigned short* qkvwb = (unsigned short*)(ws + 52748800); // 1152x384 bf16
  unsigned short* projwb= (unsigned short*)(ws + 53633536); // 384x384 bf16
  unsigned short* featb = (unsigned short*)(ws + 53928448); // 32768x384 bf16 (25.2 MB)

  hipMemsetAsync(pmax, 0, 8, stream);
  prep_means_kernel<<<1494, 192, 0, stream>>>(pos, (unsigned*)pmax, qkv_w, qkvwb,
                                              proj_w, projwb, feat, member_idx,
                                              batch_idx, fm, pm, featb);
  // kv GEMM (96 blocks, incl. wt fold) + 512 q-tiles in one 512-block launch
  kvq_kernel<<<512, 512, 0, stream>>>(fm, featb, qkvwb, qkv_b, pm, pmax, pos_w, pos_b,
                                      kh, vt, wt, q_s,
                                      0.17677669529663687f * 1.44269504088896340f);
  // fused attention + output projection (128 tok/block)
  attnproj_kernel<<<256, 512, 0, stream>>>(q_s, kh, vt, wt, projwb, proj_b, out);
}

// Round 9
// 187.241 us; speedup vs baseline: 1.0313x; 1.0313x over previous
//
#include <hip/hip_runtime.h>

typedef __attribute__((ext_vector_type(8))) short bf16x8;
typedef __attribute__((ext_vector_type(4))) float f32x4;

#define MFMA16(a,b,c) __builtin_amdgcn_mfma_f32_16x16x32_bf16((a),(b),(c),0,0,0)

__device__ __forceinline__ float b2f(unsigned short u){
  union { unsigned u; float f; } x; x.u = ((unsigned)u) << 16; return x.f;
}
__device__ __forceinline__ unsigned short f2b(float f){
  union { float f; unsigned u; } x; x.f = f;
  unsigned r = x.u + 0x7FFFu + ((x.u >> 16) & 1u);
  return (unsigned short)(r >> 16);
}
__device__ __forceinline__ unsigned pk_rne(float a, float b){
  unsigned ua = __float_as_uint(a), ub = __float_as_uint(b);
  ua += 0x7FFFu + ((ua >> 16) & 1u);
  ub += 0x7FFFu + ((ub >> 16) & 1u);
  return __builtin_amdgcn_perm(ub, ua, 0x07060302u);
}
__device__ __forceinline__ unsigned pk_trunc(float a, float b){
  return __builtin_amdgcn_perm(__float_as_uint(b), __float_as_uint(a), 0x07060302u);
}
__device__ __forceinline__ bf16x8 mk8(unsigned a, unsigned b, unsigned c, unsigned d){
  union { uint4 u; bf16x8 h; } x; x.u = make_uint4(a,b,c,d); return x.h;
}
// cluster-index bit rotation so register Sᵀ fragments align with PV's B-operand k-slots
__device__ __forceinline__ int permp(int cl){
  return (cl & 0xE0) | (((cl >> 2) & 3) << 3) | (((cl >> 4) & 1) << 2) | (cl & 3);
}

typedef __attribute__((address_space(3))) unsigned int lds_u32;
typedef const __attribute__((address_space(1))) unsigned int glb_u32;
__device__ __forceinline__ void gl_lds16(const void* g, void* l){
  __builtin_amdgcn_global_load_lds((glb_u32*)g, (lds_u32*)l, 16, 0, 0);
}

// ---------------- merged prep + cluster means ----------------
__global__ __launch_bounds__(192) void prep_means_kernel(
    const float* __restrict__ pos, unsigned* __restrict__ pmax,
    const float* __restrict__ qkv_w, unsigned short* __restrict__ qkvwb,
    const float* __restrict__ proj_w, unsigned short* __restrict__ projwb,
    const float* __restrict__ feat,
    const int* __restrict__ member_idx, const int* __restrict__ batch_idx,
    unsigned short* __restrict__ fm, float* __restrict__ pm,
    unsigned short* __restrict__ featb)
{
  int bid = blockIdx.x, t = threadIdx.x;
  if (bid < 1024){
    int g = t / 96, tl = t - g*96;
    int z = bid;
    __shared__ int bases[32];
    __shared__ float4 part[96];
    if (t < 32) bases[t] = batch_idx[z*32 + t]*8192 + member_idx[z*32 + t];
    __syncthreads();
    // pos mean: one wave-load + tree reduce on lanes 0..31
    if (t < 32){
      float2 pp = ((const float2*)pos)[bases[t]];
      #pragma unroll
      for (int off = 16; off >= 1; off >>= 1){
        pp.x += __shfl_xor(pp.x, off, 32);
        pp.y += __shfl_xor(pp.y, off, 32);
      }
      if (t == 0){ pm[z*2] = pp.x*(1.f/32.f); pm[z*2+1] = pp.y*(1.f/32.f); }
    }
    // feat: 16 gather loads in flight, then stores + accumulate
    float4 v[16]; int rows[16];
    const float4* f4 = (const float4*)feat;
    #pragma unroll
    for (int m = 0; m < 16; m++){
      rows[m] = bases[g*16 + m];
      v[m] = f4[(long)rows[m]*96 + tl];
    }
    float4 a = {0.f,0.f,0.f,0.f};
    #pragma unroll
    for (int m = 0; m < 16; m++){
      *(uint2*)(featb + (long)rows[m]*384 + tl*4) =
          make_uint2(pk_rne(v[m].x, v[m].y), pk_rne(v[m].z, v[m].w));
      a.x += v[m].x; a.y += v[m].y; a.z += v[m].z; a.w += v[m].w;
    }
    if (g == 1) part[tl] = a;
    __syncthreads();
    if (g == 0){
      float4 b = part[tl];
      a.x += b.x; a.y += b.y; a.z += b.z; a.w += b.w;
      unsigned d0 = pk_rne(a.x*(1.f/32.f), a.y*(1.f/32.f));
      unsigned d1 = pk_rne(a.z*(1.f/32.f), a.w*(1.f/32.f));
      *(uint2*)(fm + (long)z*384 + tl*4) = make_uint2(d0, d1);
    }
  } else if (bid < 1408){
    int u = (bid - 1024)*192 + t;     // [0, 73728)
    const float* in; unsigned short* o; long i;
    if (u < 55296){ in = qkv_w;  o = qkvwb;  i = u; }
    else          { in = proj_w; o = projwb; i = u - 55296; }
    const float4* p = (const float4*)(in + i*8);
    float4 a = p[0], b = p[1];
    *(uint4*)(o + i*8) = make_uint4(pk_rne(a.x,a.y), pk_rne(a.z,a.w),
                                    pk_rne(b.x,b.y), pk_rne(b.z,b.w));
  } else {
    int i = (bid - 1408)*192 + t;
    if (i < 16384){
      float4 v = ((const float4*)pos)[i];
      float m0 = fmaxf(v.x, v.z), m1 = fmaxf(v.y, v.w);
      #pragma unroll
      for (int off = 32; off >= 1; off >>= 1){
        m0 = fmaxf(m0, __shfl_xor(m0, off, 64));
        m1 = fmaxf(m1, __shfl_xor(m1, off, 64));
      }
      if ((t & 63) == 0){
        atomicMax(&pmax[0], __float_as_uint(m0));
        atomicMax(&pmax[1], __float_as_uint(m1));
      }
    }
  }
}

// ---------------- merged kv-GEMM + wt + q-GEMM, 512 blocks ----------------
__global__ __launch_bounds__(512) void kvq_kernel(
    const unsigned short* __restrict__ fm,     // (1024,384) bf16 cluster means
    const unsigned short* __restrict__ featb,  // (32768,384) bf16
    const unsigned short* __restrict__ qkvwb,  // (1152,384) bf16; rows 0..383 = Wq
    const float* __restrict__ qkv_b,           // (1152)
    const float* __restrict__ pm, const float* __restrict__ pmaxf,
    const float* __restrict__ pos_w, const float* __restrict__ pos_b,
    unsigned short* __restrict__ kh, unsigned short* __restrict__ vt,
    unsigned short* __restrict__ wt,
    unsigned short* __restrict__ q_s, float q_scale)
{
  __shared__ unsigned short As[64*64];    // 8 KB
  __shared__ unsigned short Ws[384*64];   // 48 KB
  __shared__ unsigned short wtS[256];
  const int K = 384;
  int tid = threadIdx.x;
  int lane = tid & 63, wave = tid >> 6;
  int l15 = lane & 15, quad = lane >> 4;
  int sw = l15 & 7;
  int srow = tid >> 3, sc8 = tid & 7;     // 512 thr: srow 0..63

  int qtile;
  if (blockIdx.x < 96){
    // ================= kv GEMM =================
    int mt = blockIdx.x / 6, nt = blockIdx.x - mt*6;
    int m0 = mt << 6, n0 = nt << 7;
    int b = m0 >> 8, cl0 = m0 & 255;
    const unsigned short* W = qkvwb + 384*384;
    // wt prologue: this block's 4 heads x 64 clusters (bit-identical to old bias_kernel)
    if (nt >= 3 && tid < 256){
      int lh = tid >> 6, lc = tid & 63;
      int h = ((n0 - 384) >> 5) + lh;
      int cl = cl0 + lc;
      float p0 = pm[(b*256 + cl)*2]   / pmaxf[0];
      float p1 = pm[(b*256 + cl)*2+1] / pmaxf[1];
      float bias = p0*pos_w[h*2] + p1*pos_w[h*2+1] + pos_b[h];
      unsigned short wv = f2b(exp2f(bias * 1.44269504088896340f));
      wtS[lh*64 + lc] = wv;
      wt[(((long)(b*12 + h)) << 8) + permp(cl)] = wv;
    }
    int wr = (wave >> 2) << 5, wc = (wave & 3) << 5;
    f32x4 acc[2][2];
    #pragma unroll
    for (int i = 0; i < 2; i++)
      #pragma unroll
      for (int j = 0; j < 2; j++) acc[i][j] = (f32x4){0.f,0.f,0.f,0.f};

    for (int k0 = 0; k0 < K; k0 += 64){
      __syncthreads();
      int gc8 = sc8 ^ (srow & 7);
      gl_lds16(fm + (long)(m0+srow)*K + k0 + gc8*8, As + wave*512);
      #pragma unroll
      for (int it = 0; it < 2; it++){
        int r = it*64 + srow;
        int g2 = sc8 ^ (r & 7);
        gl_lds16(W + (long)(n0+r)*K + k0 + g2*8, Ws + it*4096 + wave*512);
      }
      __syncthreads();
      #pragma unroll
      for (int kk = 0; kk < 2; kk++){
        bf16x8 af[2], bfr[2];
        #pragma unroll
        for (int i = 0; i < 2; i++)
          af[i] = *(const bf16x8*)(As + (wr + i*16 + l15)*64 + (((kk<<2)+quad) ^ sw)*8);
        #pragma unroll
        for (int j = 0; j < 2; j++)
          bfr[j] = *(const bf16x8*)(Ws + (wc + j*16 + l15)*64 + (((kk<<2)+quad) ^ sw)*8);
        #pragma unroll
        for (int i = 0; i < 2; i++)
          #pragma unroll
          for (int j = 0; j < 2; j++)
            acc[i][j] = MFMA16(af[i], bfr[j], acc[i][j]);
      }
    }

    #pragma unroll
    for (int j = 0; j < 2; j++){
      int col = n0 + wc + j*16 + l15;
      float bv = qkv_b[384 + col];
      #pragma unroll
      for (int i = 0; i < 2; i++){
        #pragma unroll
        for (int r = 0; r < 4; r++){
          float v = acc[i][j][r] + bv;
          int lr = wr + i*16 + quad*4 + r;     // local row 0..63
          int cl = cl0 + lr;
          if (col < 384){
            int h = col >> 5, ch = col & 31;
            kh[((((long)b*12 + h)*256 + cl)*32) + ch] = f2b(v);
          } else {
            int cn = col - 384;
            int h = cn >> 5, ch = cn & 31;
            int pp = permp(cl);
            int c8 = (pp >> 3) ^ (ch & 7);
            float w = b2f(wtS[(wave & 3)*64 + lr]);
            vt[(((long)b*12 + h)*32 + ch)*256 + c8*8 + (pp & 7)] = f2b(v * w);
          }
        }
      }
    }
    qtile = 416 + blockIdx.x;
  } else {
    qtile = blockIdx.x - 96;
  }

  // ================= q GEMM (single-buffer, 2 blocks/CU structure) =================
  {
    int m0 = qtile << 6;
    f32x4 acc[4][3];
    #pragma unroll
    for (int i = 0; i < 4; i++)
      #pragma unroll
      for (int j = 0; j < 3; j++) acc[i][j] = (f32x4){0.f,0.f,0.f,0.f};

    for (int k0 = 0; k0 < K; k0 += 64){
      __syncthreads();
      int gc8 = sc8 ^ (srow & 7);
      gl_lds16(featb + (long)(m0+srow)*K + k0 + gc8*8, As + wave*512);
      #pragma unroll
      for (int it = 0; it < 6; it++){
        int r = it*64 + srow;
        int g2 = sc8 ^ (r & 7);
        gl_lds16(qkvwb + (long)r*K + k0 + g2*8, Ws + it*4096 + wave*512);
      }
      __syncthreads();
      #pragma unroll
      for (int kk = 0; kk < 2; kk++){
        bf16x8 af[4];
        #pragma unroll
        for (int i = 0; i < 4; i++)
          af[i] = *(const bf16x8*)(As + (i*16 + l15)*64 + (((kk<<2)+quad) ^ sw)*8);
        #pragma unroll
        for (int j = 0; j < 3; j++){
          bf16x8 bfr = *(const bf16x8*)(Ws + (wave*48 + j*16 + l15)*64 + (((kk<<2)+quad) ^ sw)*8);
          #pragma unroll
          for (int i = 0; i < 4; i++)
            acc[i][j] = MFMA16(af[i], bfr, acc[i][j]);
        }
      }
    }

    #pragma unroll
    for (int j = 0; j < 3; j++){
      int col = wave*48 + j*16 + l15;
      float bv = qkv_b[col];
      #pragma unroll
      for (int i = 0; i < 4; i++){
        int row0 = m0 + i*16 + quad*4;
        #pragma unroll
        for (int r = 0; r < 4; r++){
          float v = (acc[i][j][r] + bv) * q_scale;
          int row = row0 + r;
          int bb = row >> 13, tok = row & 8191;
          q_s[((((long)(bb*12 + (col >> 5))) << 13) + tok)*32 + (col & 31)] = f2b(v);
        }
      }
    }
  }
}

// ---------------- FUSED attention + proj (r7 shape + K-swizzle) ----------------
// block = (b, 64 tokens), 512 thr / 8 waves, 512 blocks = 2 blocks/CU (73 KB LDS):
// the per-iteration stage stall is hidden by the co-resident block (r8 lesson:
// 128-tok blocks give only 256 blocks = 1/CU -> no overlap partner -> regression).
// K-read bank fix (r8-proven): keyS XOR-swizzle col8 ^= (row>>1)&3 via pre-swizzled
// GLOBAL source (m173: global_load_lds writes linearly) + same XOR on read.
// 64 B K-row stride made 16 lanes alias 2 banks (8-way, 3.3 M conflict cycles).
__global__ __launch_bounds__(512, 4) void attnproj_kernel(
    const unsigned short* __restrict__ qhm,    // (B*H,8192,32) bf16, scale*log2e folded
    const unsigned short* __restrict__ kh,     // (B,H,256,32) bf16
    const unsigned short* __restrict__ vt,     // (B,H,32,256) bf16, permp+swizzled, w-folded
    const unsigned short* __restrict__ wt,     // (B*H,256) bf16, permp'd
    const unsigned short* __restrict__ projwb, // (384,384) bf16
    const float* __restrict__ proj_b,
    float* __restrict__ out)                   // (B*8192,384) f32
{
  __shared__ unsigned short keyS[16384];       // 32 KB: [head][256][32], col8 ^= (row>>1)&3
  __shared__ unsigned short vTS[16384];        // 32 KB: [head][32][256] swizzled
  __shared__ unsigned short oS[64*64];         // 8 KB: [tok][ch oct^sw]
  __shared__ unsigned short wS[512];           // 1 KB: [head][256]

  int bid = blockIdx.x;
  int b = bid >> 7;
  int t0 = (bid & 127) << 6;
  int tid = threadIdx.x, lane = tid & 63, wave = tid >> 6;
  int l15 = lane & 15, quad = lane >> 4;
  int sw = l15 & 7;
  int hsel = wave >> 2, ti = wave & 3;

  f32x4 acc[4][3];
  #pragma unroll
  for (int i = 0; i < 4; i++)
    #pragma unroll
    for (int j = 0; j < 3; j++) acc[i][j] = (f32x4){0.f,0.f,0.f,0.f};

  for (int it = 0; it < 6; it++){
    int h0 = 2*it;
    // ---- stage head-pair (32 KB K + 32 KB V + 1 KB w) ----
    const unsigned short* ks = kh + ((long)b*12 + h0)*8192;   // 2 heads contiguous
    const unsigned short* vs = vt + ((long)b*12 + h0)*8192;
    #pragma unroll
    for (int p = 0; p < 4; p++){
      // K: pre-swizzled global source (LDS dest linear: base + lane*16B)
      int u = p*512 + wave*64 + lane;          // 16B-unit index, 0..2047
      int krow = u >> 2;                       // row 0..511 across the head pair
      int kc = (u & 3) ^ ((krow >> 1) & 3);
      gl_lds16(ks + krow*32 + kc*8, keyS + p*4096 + wave*512);
      gl_lds16(vs + p*4096 + tid*8, vTS + p*4096 + wave*512);
    }
    if (wave == 0)
      gl_lds16(wt + ((long)b*12 + h0)*256 + lane*8, wS);

    // q load overlaps staging (result needed after barrier)
    long bh = (long)b*12 + h0 + hsel;
    bf16x8 aq = *(const bf16x8*)(qhm + (bh*8192 + t0 + ti*16 + l15)*32 + quad*8);
    __syncthreads();                          // stage drained (vmcnt0 before barrier)

    const unsigned short* kb = keyS + hsel*8192;
    const unsigned short* vb = vTS  + hsel*8192;
    const unsigned short* wb = wS   + hsel*256;

    f32x4 o0 = {0.f,0.f,0.f,0.f}, o1 = {0.f,0.f,0.f,0.f}, os = {0.f,0.f,0.f,0.f};
    #pragma unroll
    for (int ks8 = 0; ks8 < 8; ks8++){
      int r0 = 32*ks8 + l15, r1 = r0 + 16;     // local K rows this k-slot
      bf16x8 bk0 = *(const bf16x8*)(kb + r0*32 + (quad ^ ((r0 >> 1) & 3))*8);
      bf16x8 bk1 = *(const bf16x8*)(kb + r1*32 + (quad ^ ((r1 >> 1) & 3))*8);
      const f32x4 z4 = {0.f,0.f,0.f,0.f};
      f32x4 s0 = MFMA16(bk0, aq, z4);
      f32x4 s1 = MFMA16(bk1, aq, z4);
      #pragma unroll
      for (int c = 0; c < 4; c++){ s0[c] = exp2f(s0[c]); s1[c] = exp2f(s1[c]); }
      bf16x8 pf = mk8(pk_trunc(s0[0],s0[1]), pk_trunc(s0[2],s0[3]),
                      pk_trunc(s1[0],s1[1]), pk_trunc(s1[2],s1[3]));
      int c8 = (4*ks8 + quad) ^ sw;
      bf16x8 a0 = *(const bf16x8*)(vb + l15*256      + c8*8);
      bf16x8 a1 = *(const bf16x8*)(vb + (16+l15)*256 + c8*8);
      bf16x8 wf = *(const bf16x8*)(wb + ks8*32 + quad*8);
      o0 = MFMA16(a0, pf, o0);
      o1 = MFMA16(a1, pf, o1);
      os = MFMA16(wf, pf, os);
    }

    // normalize + store O tile [64 tok][64 ch] bf16 with oct^sw swizzle
    // (O bf16-rounded at the same point as the old global ao write -> bit-identical)
    float inv = 1.f / os[0];
    int tokLoc = ti*16 + l15;                 // tokLoc&7 == sw
    int oct0 = hsel*4 + (quad >> 1);          // o0: ch hsel*32+quad*4..+3 ; o1: +16
    int wi = (quad & 1)*4;
    *(uint2*)(oS + tokLoc*64 + ((oct0 ^ sw)*8 + wi)) =
        make_uint2(pk_rne(o0[0]*inv, o0[1]*inv), pk_rne(o0[2]*inv, o0[3]*inv));
    *(uint2*)(oS + tokLoc*64 + (((oct0+2) ^ sw)*8 + wi)) =
        make_uint2(pk_rne(o1[0]*inv, o1[1]*inv), pk_rne(o1[2]*inv, o1[3]*inv));
    __syncthreads();                          // O visible; keyS/vTS reads complete

    // proj accumulate: BK=64 (this head-pair's channels); B direct from L2
    #pragma unroll
    for (int kk = 0; kk < 2; kk++){
      bf16x8 af[4];
      #pragma unroll
      for (int i = 0; i < 4; i++)
        af[i] = *(const bf16x8*)(oS + (i*16 + l15)*64 + (((kk<<2)+quad) ^ sw)*8);
      #pragma unroll
      for (int j = 0; j < 3; j++){
        bf16x8 bfr = *(const bf16x8*)(projwb + (long)(wave*48 + j*16 + l15)*384
                                      + it*64 + (kk*4 + quad)*8);
        #pragma unroll
        for (int i = 0; i < 4; i++)
          acc[i][j] = MFMA16(af[i], bfr, acc[i][j]);
      }
    }
    // no barrier here: next stage writes keyS/vTS only (not oS), and next oS
    // write happens after the next barrier, by which time all proj reads are done
  }

  // epilogue: f32 token-major
  #pragma unroll
  for (int j = 0; j < 3; j++){
    int col = wave*48 + j*16 + l15;
    float bv = proj_b[col];
    #pragma unroll
    for (int i = 0; i < 4; i++){
      long row0 = (long)b*8192 + t0 + i*16 + quad*4;
      #pragma unroll
      for (int r = 0; r < 4; r++)
        out[(row0 + r)*384 + col] = acc[i][j][r] + bv;
    }
  }
}

extern "C" void kernel_launch(void* const* d_in, const int* in_sizes, int n_in,
                              void* d_out, int out_size, void* d_ws, size_t ws_size,
                              hipStream_t stream)
{
  const float* pos      = (const float*)d_in[0];
  const float* feat     = (const float*)d_in[1];
  const int* member_idx = (const int*)d_in[2];
  const int* batch_idx  = (const int*)d_in[3];
  const float* qkv_w    = (const float*)d_in[4];
  const float* qkv_b    = (const float*)d_in[5];
  const float* pos_w    = (const float*)d_in[6];
  const float* pos_b    = (const float*)d_in[7];
  const float* proj_w   = (const float*)d_in[8];
  const float* proj_b   = (const float*)d_in[9];
  float* out = (float*)d_out;

  char* ws = (char*)d_ws;
  float* pmax           = (float*)ws;                       // 8 B
  float* pm             = (float*)(ws + 256);               // 8 KB
  unsigned short* fm    = (unsigned short*)(ws + 8704);     // 1024x384 bf16
  unsigned short* kh    = (unsigned short*)(ws + 795136);   // 4x12x256x32 bf16
  unsigned short* vt    = (unsigned short*)(ws + 1581568);  // 4x12x32x256 bf16
  unsigned short* wt    = (unsigned short*)(ws + 2368000);  // 4x12x256 bf16
  unsigned short* q_s   = (unsigned short*)(ws + 2417152);  // 48x8192x32 bf16 (head-major)
  unsigned short* qkvwb = (unsigned short*)(ws + 52748800); // 1152x384 bf16
  unsigned short* projwb= (unsigned short*)(ws + 53633536); // 384x384 bf16
  unsigned short* featb = (unsigned short*)(ws + 53928448); // 32768x384 bf16 (25.2 MB)

  hipMemsetAsync(pmax, 0, 8, stream);
  prep_means_kernel<<<1494, 192, 0, stream>>>(pos, (unsigned*)pmax, qkv_w, qkvwb,
                                              proj_w, projwb, feat, member_idx,
                                              batch_idx, fm, pm, featb);
  // kv GEMM (96 blocks, incl. wt fold) + 512 q-tiles in one 512-block launch
  kvq_kernel<<<512, 512, 0, stream>>>(fm, featb, qkvwb, qkv_b, pm, pmax, pos_w, pos_b,
                                      kh, vt, wt, q_s,
                                      0.17677669529663687f * 1.44269504088896340f);
  // fused attention + output projection (64 tok/block, 2 blocks/CU)
  attnproj_kernel<<<512, 512, 0, stream>>>(q_s, kh, vt, wt, projwb, proj_b, out);
}

// Round 11
// 183.456 us; speedup vs baseline: 1.0526x; 1.0206x over previous
//
#include <hip/hip_runtime.h>

typedef __attribute__((ext_vector_type(8))) short bf16x8;
typedef __attribute__((ext_vector_type(4))) float f32x4;

#define MFMA16(a,b,c) __builtin_amdgcn_mfma_f32_16x16x32_bf16((a),(b),(c),0,0,0)

__device__ __forceinline__ float b2f(unsigned short u){
  union { unsigned u; float f; } x; x.u = ((unsigned)u) << 16; return x.f;
}
__device__ __forceinline__ unsigned short f2b(float f){
  union { float f; unsigned u; } x; x.f = f;
  unsigned r = x.u + 0x7FFFu + ((x.u >> 16) & 1u);
  return (unsigned short)(r >> 16);
}
__device__ __forceinline__ unsigned pk_rne(float a, float b){
  unsigned ua = __float_as_uint(a), ub = __float_as_uint(b);
  ua += 0x7FFFu + ((ua >> 16) & 1u);
  ub += 0x7FFFu + ((ub >> 16) & 1u);
  return __builtin_amdgcn_perm(ub, ua, 0x07060302u);
}
__device__ __forceinline__ unsigned pk_trunc(float a, float b){
  return __builtin_amdgcn_perm(__float_as_uint(b), __float_as_uint(a), 0x07060302u);
}
__device__ __forceinline__ bf16x8 mk8(unsigned a, unsigned b, unsigned c, unsigned d){
  union { uint4 u; bf16x8 h; } x; x.u = make_uint4(a,b,c,d); return x.h;
}
// cluster-index bit rotation so register Sᵀ fragments align with PV's B-operand k-slots
__device__ __forceinline__ int permp(int cl){
  return (cl & 0xE0) | (((cl >> 2) & 3) << 3) | (((cl >> 4) & 1) << 2) | (cl & 3);
}

typedef __attribute__((address_space(3))) unsigned int lds_u32;
typedef const __attribute__((address_space(1))) unsigned int glb_u32;
__device__ __forceinline__ void gl_lds16(const void* g, void* l){
  __builtin_amdgcn_global_load_lds((glb_u32*)g, (lds_u32*)l, 16, 0, 0);
}

// ---------------- merged prep + cluster means ----------------
__global__ __launch_bounds__(192) void prep_means_kernel(
    const float* __restrict__ pos, unsigned* __restrict__ pmax,
    const float* __restrict__ qkv_w, unsigned short* __restrict__ qkvwb,
    const float* __restrict__ proj_w, unsigned short* __restrict__ projwb,
    const float* __restrict__ feat,
    const int* __restrict__ member_idx, const int* __restrict__ batch_idx,
    unsigned short* __restrict__ fm, float* __restrict__ pm,
    unsigned short* __restrict__ featb)
{
  int bid = blockIdx.x, t = threadIdx.x;
  if (bid < 1024){
    int g = t / 96, tl = t - g*96;
    int z = bid;
    __shared__ int bases[32];
    __shared__ float4 part[96];
    if (t < 32) bases[t] = batch_idx[z*32 + t]*8192 + member_idx[z*32 + t];
    __syncthreads();
    // pos mean: one wave-load + tree reduce on lanes 0..31
    if (t < 32){
      float2 pp = ((const float2*)pos)[bases[t]];
      #pragma unroll
      for (int off = 16; off >= 1; off >>= 1){
        pp.x += __shfl_xor(pp.x, off, 32);
        pp.y += __shfl_xor(pp.y, off, 32);
      }
      if (t == 0){ pm[z*2] = pp.x*(1.f/32.f); pm[z*2+1] = pp.y*(1.f/32.f); }
    }
    // feat: 16 gather loads in flight, then stores + accumulate
    float4 v[16]; int rows[16];
    const float4* f4 = (const float4*)feat;
    #pragma unroll
    for (int m = 0; m < 16; m++){
      rows[m] = bases[g*16 + m];
      v[m] = f4[(long)rows[m]*96 + tl];
    }
    float4 a = {0.f,0.f,0.f,0.f};
    #pragma unroll
    for (int m = 0; m < 16; m++){
      *(uint2*)(featb + (long)rows[m]*384 + tl*4) =
          make_uint2(pk_rne(v[m].x, v[m].y), pk_rne(v[m].z, v[m].w));
      a.x += v[m].x; a.y += v[m].y; a.z += v[m].z; a.w += v[m].w;
    }
    if (g == 1) part[tl] = a;
    __syncthreads();
    if (g == 0){
      float4 b = part[tl];
      a.x += b.x; a.y += b.y; a.z += b.z; a.w += b.w;
      unsigned d0 = pk_rne(a.x*(1.f/32.f), a.y*(1.f/32.f));
      unsigned d1 = pk_rne(a.z*(1.f/32.f), a.w*(1.f/32.f));
      *(uint2*)(fm + (long)z*384 + tl*4) = make_uint2(d0, d1);
    }
  } else if (bid < 1408){
    int u = (bid - 1024)*192 + t;     // [0, 73728)
    const float* in; unsigned short* o; long i;
    if (u < 55296){ in = qkv_w;  o = qkvwb;  i = u; }
    else          { in = proj_w; o = projwb; i = u - 55296; }
    const float4* p = (const float4*)(in + i*8);
    float4 a = p[0], b = p[1];
    *(uint4*)(o + i*8) = make_uint4(pk_rne(a.x,a.y), pk_rne(a.z,a.w),
                                    pk_rne(b.x,b.y), pk_rne(b.z,b.w));
  } else {
    int i = (bid - 1408)*192 + t;
    if (i < 16384){
      float4 v = ((const float4*)pos)[i];
      float m0 = fmaxf(v.x, v.z), m1 = fmaxf(v.y, v.w);
      #pragma unroll
      for (int off = 32; off >= 1; off >>= 1){
        m0 = fmaxf(m0, __shfl_xor(m0, off, 64));
        m1 = fmaxf(m1, __shfl_xor(m1, off, 64));
      }
      if ((t & 63) == 0){
        atomicMax(&pmax[0], __float_as_uint(m0));
        atomicMax(&pmax[1], __float_as_uint(m1));
      }
    }
  }
}

// ---------------- merged kv-GEMM + wt + q-GEMM, 512 blocks ----------------
// kh is written PRE-SWIZZLED: within each cluster row, 16B unit
// unit' = (ch>>3) ^ ((cl>>1)&3). attnproj stages kh LINEARLY (fast coalesced
// global_load_lds) and applies the same XOR on the LDS read -> conflict-free
// K-reads without the r9 permuted-global-source staging penalty.
__global__ __launch_bounds__(512) void kvq_kernel(
    const unsigned short* __restrict__ fm,     // (1024,384) bf16 cluster means
    const unsigned short* __restrict__ featb,  // (32768,384) bf16
    const unsigned short* __restrict__ qkvwb,  // (1152,384) bf16; rows 0..383 = Wq
    const float* __restrict__ qkv_b,           // (1152)
    const float* __restrict__ pm, const float* __restrict__ pmaxf,
    const float* __restrict__ pos_w, const float* __restrict__ pos_b,
    unsigned short* __restrict__ kh, unsigned short* __restrict__ vt,
    unsigned short* __restrict__ wt,
    unsigned short* __restrict__ q_s, float q_scale)
{
  __shared__ unsigned short As[64*64];    // 8 KB
  __shared__ unsigned short Ws[384*64];   // 48 KB
  __shared__ unsigned short wtS[256];
  const int K = 384;
  int tid = threadIdx.x;
  int lane = tid & 63, wave = tid >> 6;
  int l15 = lane & 15, quad = lane >> 4;
  int sw = l15 & 7;
  int srow = tid >> 3, sc8 = tid & 7;     // 512 thr: srow 0..63

  int qtile;
  if (blockIdx.x < 96){
    // ================= kv GEMM =================
    int mt = blockIdx.x / 6, nt = blockIdx.x - mt*6;
    int m0 = mt << 6, n0 = nt << 7;
    int b = m0 >> 8, cl0 = m0 & 255;
    const unsigned short* W = qkvwb + 384*384;
    // wt prologue: this block's 4 heads x 64 clusters (bit-identical to old bias_kernel)
    if (nt >= 3 && tid < 256){
      int lh = tid >> 6, lc = tid & 63;
      int h = ((n0 - 384) >> 5) + lh;
      int cl = cl0 + lc;
      float p0 = pm[(b*256 + cl)*2]   / pmaxf[0];
      float p1 = pm[(b*256 + cl)*2+1] / pmaxf[1];
      float bias = p0*pos_w[h*2] + p1*pos_w[h*2+1] + pos_b[h];
      unsigned short wv = f2b(exp2f(bias * 1.44269504088896340f));
      wtS[lh*64 + lc] = wv;
      wt[(((long)(b*12 + h)) << 8) + permp(cl)] = wv;
    }
    int wr = (wave >> 2) << 5, wc = (wave & 3) << 5;
    f32x4 acc[2][2];
    #pragma unroll
    for (int i = 0; i < 2; i++)
      #pragma unroll
      for (int j = 0; j < 2; j++) acc[i][j] = (f32x4){0.f,0.f,0.f,0.f};

    for (int k0 = 0; k0 < K; k0 += 64){
      __syncthreads();
      int gc8 = sc8 ^ (srow & 7);
      gl_lds16(fm + (long)(m0+srow)*K + k0 + gc8*8, As + wave*512);
      #pragma unroll
      for (int it = 0; it < 2; it++){
        int r = it*64 + srow;
        int g2 = sc8 ^ (r & 7);
        gl_lds16(W + (long)(n0+r)*K + k0 + g2*8, Ws + it*4096 + wave*512);
      }
      __syncthreads();
      #pragma unroll
      for (int kk = 0; kk < 2; kk++){
        bf16x8 af[2], bfr[2];
        #pragma unroll
        for (int i = 0; i < 2; i++)
          af[i] = *(const bf16x8*)(As + (wr + i*16 + l15)*64 + (((kk<<2)+quad) ^ sw)*8);
        #pragma unroll
        for (int j = 0; j < 2; j++)
          bfr[j] = *(const bf16x8*)(Ws + (wc + j*16 + l15)*64 + (((kk<<2)+quad) ^ sw)*8);
        #pragma unroll
        for (int i = 0; i < 2; i++)
          #pragma unroll
          for (int j = 0; j < 2; j++)
            acc[i][j] = MFMA16(af[i], bfr[j], acc[i][j]);
      }
    }

    #pragma unroll
    for (int j = 0; j < 2; j++){
      int col = n0 + wc + j*16 + l15;
      float bv = qkv_b[384 + col];
      #pragma unroll
      for (int i = 0; i < 2; i++){
        #pragma unroll
        for (int r = 0; r < 4; r++){
          float v = acc[i][j][r] + bv;
          int lr = wr + i*16 + quad*4 + r;     // local row 0..63
          int cl = cl0 + lr;
          if (col < 384){
            int h = col >> 5, ch = col & 31;
            int cu = ((ch >> 3) ^ ((cl >> 1) & 3));   // pre-swizzled 16B unit
            kh[((((long)b*12 + h)*256 + cl)*32) + cu*8 + (ch & 7)] = f2b(v);
          } else {
            int cn = col - 384;
            int h = cn >> 5, ch = cn & 31;
            int pp = permp(cl);
            int c8 = (pp >> 3) ^ (ch & 7);
            float w = b2f(wtS[(wave & 3)*64 + lr]);
            vt[(((long)b*12 + h)*32 + ch)*256 + c8*8 + (pp & 7)] = f2b(v * w);
          }
        }
      }
    }
    qtile = 416 + blockIdx.x;
  } else {
    qtile = blockIdx.x - 96;
  }

  // ================= q GEMM (single-buffer, 2 blocks/CU structure) =================
  {
    int m0 = qtile << 6;
    f32x4 acc[4][3];
    #pragma unroll
    for (int i = 0; i < 4; i++)
      #pragma unroll
      for (int j = 0; j < 3; j++) acc[i][j] = (f32x4){0.f,0.f,0.f,0.f};

    for (int k0 = 0; k0 < K; k0 += 64){
      __syncthreads();
      int gc8 = sc8 ^ (srow & 7);
      gl_lds16(featb + (long)(m0+srow)*K + k0 + gc8*8, As + wave*512);
      #pragma unroll
      for (int it = 0; it < 6; it++){
        int r = it*64 + srow;
        int g2 = sc8 ^ (r & 7);
        gl_lds16(qkvwb + (long)r*K + k0 + g2*8, Ws + it*4096 + wave*512);
      }
      __syncthreads();
      #pragma unroll
      for (int kk = 0; kk < 2; kk++){
        bf16x8 af[4];
        #pragma unroll
        for (int i = 0; i < 4; i++)
          af[i] = *(const bf16x8*)(As + (i*16 + l15)*64 + (((kk<<2)+quad) ^ sw)*8);
        #pragma unroll
        for (int j = 0; j < 3; j++){
          bf16x8 bfr = *(const bf16x8*)(Ws + (wave*48 + j*16 + l15)*64 + (((kk<<2)+quad) ^ sw)*8);
          #pragma unroll
          for (int i = 0; i < 4; i++)
            acc[i][j] = MFMA16(af[i], bfr, acc[i][j]);
        }
      }
    }

    #pragma unroll
    for (int j = 0; j < 3; j++){
      int col = wave*48 + j*16 + l15;
      float bv = qkv_b[col];
      #pragma unroll
      for (int i = 0; i < 4; i++){
        int row0 = m0 + i*16 + quad*4;
        #pragma unroll
        for (int r = 0; r < 4; r++){
          float v = (acc[i][j][r] + bv) * q_scale;
          int row = row0 + r;
          int bb = row >> 13, tok = row & 8191;
          q_s[((((long)(bb*12 + (col >> 5))) << 13) + tok)*32 + (col & 31)] = f2b(v);
        }
      }
    }
  }
}

// ---------------- FUSED attention + proj (r7 shape; kh pre-swizzled in global) ----------------
// block = (b, 64 tokens), 512 thr / 8 waves, 512 blocks = 2 blocks/CU (73 KB LDS).
// Staging of kh is LINEAR (r7's fast coalesced pattern) because the producer
// already permuted each row's 16B units by (cl>>1)&3; the K-read applies the
// same XOR -> conflict-free (r9's win) without the permuted-global-source
// staging penalty (r9's loss).
__global__ __launch_bounds__(512, 4) void attnproj_kernel(
    const unsigned short* __restrict__ qhm,    // (B*H,8192,32) bf16, scale*log2e folded
    const unsigned short* __restrict__ kh,     // (B,H,256,32) bf16, unit-swizzled
    const unsigned short* __restrict__ vt,     // (B,H,32,256) bf16, permp+swizzled, w-folded
    const unsigned short* __restrict__ wt,     // (B*H,256) bf16, permp'd
    const unsigned short* __restrict__ projwb, // (384,384) bf16
    const float* __restrict__ proj_b,
    float* __restrict__ out)                   // (B*8192,384) f32
{
  __shared__ unsigned short keyS[16384];       // 32 KB: [head][256][32], unit-swizzled
  __shared__ unsigned short vTS[16384];        // 32 KB: [head][32][256] swizzled
  __shared__ unsigned short oS[64*64];         // 8 KB: [tok][ch oct^sw]
  __shared__ unsigned short wS[512];           // 1 KB: [head][256]

  int bid = blockIdx.x;
  int b = bid >> 7;
  int t0 = (bid & 127) << 6;
  int tid = threadIdx.x, lane = tid & 63, wave = tid >> 6;
  int l15 = lane & 15, quad = lane >> 4;
  int sw = l15 & 7;
  int hsel = wave >> 2, ti = wave & 3;

  f32x4 acc[4][3];
  #pragma unroll
  for (int i = 0; i < 4; i++)
    #pragma unroll
    for (int j = 0; j < 3; j++) acc[i][j] = (f32x4){0.f,0.f,0.f,0.f};

  for (int it = 0; it < 6; it++){
    int h0 = 2*it;
    // ---- stage head-pair (32 KB K + 32 KB V + 1 KB w), all LINEAR ----
    const unsigned short* ks = kh + ((long)b*12 + h0)*8192;   // 2 heads contiguous
    const unsigned short* vs = vt + ((long)b*12 + h0)*8192;
    #pragma unroll
    for (int p = 0; p < 4; p++){
      gl_lds16(ks + p*4096 + tid*8, keyS + p*4096 + wave*512);
      gl_lds16(vs + p*4096 + tid*8, vTS + p*4096 + wave*512);
    }
    if (wave == 0)
      gl_lds16(wt + ((long)b*12 + h0)*256 + lane*8, wS);

    // q load overlaps staging (result needed after barrier)
    long bh = (long)b*12 + h0 + hsel;
    bf16x8 aq = *(const bf16x8*)(qhm + (bh*8192 + t0 + ti*16 + l15)*32 + quad*8);
    __syncthreads();                          // stage drained (vmcnt0 before barrier)

    const unsigned short* kb = keyS + hsel*8192;
    const unsigned short* vb = vTS  + hsel*8192;
    const unsigned short* wb = wS   + hsel*256;

    f32x4 o0 = {0.f,0.f,0.f,0.f}, o1 = {0.f,0.f,0.f,0.f}, os = {0.f,0.f,0.f,0.f};
    #pragma unroll
    for (int ks8 = 0; ks8 < 8; ks8++){
      int r0 = 32*ks8 + l15, r1 = r0 + 16;     // local K rows this k-slot
      bf16x8 bk0 = *(const bf16x8*)(kb + r0*32 + (quad ^ ((r0 >> 1) & 3))*8);
      bf16x8 bk1 = *(const bf16x8*)(kb + r1*32 + (quad ^ ((r1 >> 1) & 3))*8);
      const f32x4 z4 = {0.f,0.f,0.f,0.f};
      f32x4 s0 = MFMA16(bk0, aq, z4);
      f32x4 s1 = MFMA16(bk1, aq, z4);
      #pragma unroll
      for (int c = 0; c < 4; c++){ s0[c] = exp2f(s0[c]); s1[c] = exp2f(s1[c]); }
      bf16x8 pf = mk8(pk_trunc(s0[0],s0[1]), pk_trunc(s0[2],s0[3]),
                      pk_trunc(s1[0],s1[1]), pk_trunc(s1[2],s1[3]));
      int c8 = (4*ks8 + quad) ^ sw;
      bf16x8 a0 = *(const bf16x8*)(vb + l15*256      + c8*8);
      bf16x8 a1 = *(const bf16x8*)(vb + (16+l15)*256 + c8*8);
      bf16x8 wf = *(const bf16x8*)(wb + ks8*32 + quad*8);
      o0 = MFMA16(a0, pf, o0);
      o1 = MFMA16(a1, pf, o1);
      os = MFMA16(wf, pf, os);
    }

    // normalize + store O tile [64 tok][64 ch] bf16 with oct^sw swizzle
    // (O bf16-rounded at the same point as the old global ao write -> bit-identical)
    float inv = 1.f / os[0];
    int tokLoc = ti*16 + l15;                 // tokLoc&7 == sw
    int oct0 = hsel*4 + (quad >> 1);          // o0: ch hsel*32+quad*4..+3 ; o1: +16
    int wi = (quad & 1)*4;
    *(uint2*)(oS + tokLoc*64 + ((oct0 ^ sw)*8 + wi)) =
        make_uint2(pk_rne(o0[0]*inv, o0[1]*inv), pk_rne(o0[2]*inv, o0[3]*inv));
    *(uint2*)(oS + tokLoc*64 + (((oct0+2) ^ sw)*8 + wi)) =
        make_uint2(pk_rne(o1[0]*inv, o1[1]*inv), pk_rne(o1[2]*inv, o1[3]*inv));
    __syncthreads();                          // O visible; keyS/vTS reads complete

    // proj accumulate: BK=64 (this head-pair's channels); B direct from L2
    #pragma unroll
    for (int kk = 0; kk < 2; kk++){
      bf16x8 af[4];
      #pragma unroll
      for (int i = 0; i < 4; i++)
        af[i] = *(const bf16x8*)(oS + (i*16 + l15)*64 + (((kk<<2)+quad) ^ sw)*8);
      #pragma unroll
      for (int j = 0; j < 3; j++){
        bf16x8 bfr = *(const bf16x8*)(projwb + (long)(wave*48 + j*16 + l15)*384
                                      + it*64 + (kk*4 + quad)*8);
        #pragma unroll
        for (int i = 0; i < 4; i++)
          acc[i][j] = MFMA16(af[i], bfr, acc[i][j]);
      }
    }
    // no barrier here: next stage writes keyS/vTS only (not oS), and next oS
    // write happens after the next barrier, by which time all proj reads are done
  }

  // epilogue: f32 token-major
  #pragma unroll
  for (int j = 0; j < 3; j++){
    int col = wave*48 + j*16 + l15;
    float bv = proj_b[col];
    #pragma unroll
    for (int i = 0; i < 4; i++){
      long row0 = (long)b*8192 + t0 + i*16 + quad*4;
      #pragma unroll
      for (int r = 0; r < 4; r++)
        out[(row0 + r)*384 + col] = acc[i][j][r] + bv;
    }
  }
}

extern "C" void kernel_launch(void* const* d_in, const int* in_sizes, int n_in,
                              void* d_out, int out_size, void* d_ws, size_t ws_size,
                              hipStream_t stream)
{
  const float* pos      = (const float*)d_in[0];
  const float* feat     = (const float*)d_in[1];
  const int* member_idx = (const int*)d_in[2];
  const int* batch_idx  = (const int*)d_in[3];
  const float* qkv_w    = (const float*)d_in[4];
  const float* qkv_b    = (const float*)d_in[5];
  const float* pos_w    = (const float*)d_in[6];
  const float* pos_b    = (const float*)d_in[7];
  const float* proj_w   = (const float*)d_in[8];
  const float* proj_b   = (const float*)d_in[9];
  float* out = (float*)d_out;

  char* ws = (char*)d_ws;
  float* pmax           = (float*)ws;                       // 8 B
  float* pm             = (float*)(ws + 256);               // 8 KB
  unsigned short* fm    = (unsigned short*)(ws + 8704);     // 1024x384 bf16
  unsigned short* kh    = (unsigned short*)(ws + 795136);   // 4x12x256x32 bf16
  unsigned short* vt    = (unsigned short*)(ws + 1581568);  // 4x12x32x256 bf16
  unsigned short* wt    = (unsigned short*)(ws + 2368000);  // 4x12x256 bf16
  unsigned short* q_s   = (unsigned short*)(ws + 2417152);  // 48x8192x32 bf16 (head-major)
  unsigned short* qkvwb = (unsigned short*)(ws + 52748800); // 1152x384 bf16
  unsigned short* projwb= (unsigned short*)(ws + 53633536); // 384x384 bf16
  unsigned short* featb = (unsigned short*)(ws + 53928448); // 32768x384 bf16 (25.2 MB)

  hipMemsetAsync(pmax, 0, 8, stream);
  prep_means_kernel<<<1494, 192, 0, stream>>>(pos, (unsigned*)pmax, qkv_w, qkvwb,
                                              proj_w, projwb, feat, member_idx,
                                              batch_idx, fm, pm, featb);
  // kv GEMM (96 blocks, incl. wt fold) + 512 q-tiles in one 512-block launch
  kvq_kernel<<<512, 512, 0, stream>>>(fm, featb, qkvwb, qkv_b, pm, pmax, pos_w, pos_b,
                                      kh, vt, wt, q_s,
                                      0.17677669529663687f * 1.44269504088896340f);
  // fused attention + output projection (64 tok/block, 2 blocks/CU)
  attnproj_kernel<<<512, 512, 0, stream>>>(q_s, kh, vt, wt, projwb, proj_b, out);
}